// Round 1
// baseline (177.836 us; speedup 1.0000x reference)
//
#include <hip/hip_runtime.h>

#define DD 256
#define BB 8
#define SS 1024
#define XSTRIDE 264   // f16 elems per LDS row (528 B, 16B-aligned)

// ws layout per layer (bytes): Mtab 131072 | Ptab 131072 | Itab 262144 = 524288
#define LAYER_BYTES 524288
#define PTAB_OFF    131072
#define ITAB_OFF    262144
#define WS_NEEDED   (2 * LAYER_BYTES)

typedef _Float16 half8  __attribute__((ext_vector_type(8)));
typedef _Float16 half2t __attribute__((ext_vector_type(2)));
typedef __fp16   fp16x2 __attribute__((ext_vector_type(2)));
typedef __attribute__((ext_vector_type(4))) float float4v;

__device__ __forceinline__ half2t pkrtz(float a, float b) {
    union { fp16x2 f; half2t h; } cv;
    cv.f = __builtin_amdgcn_cvt_pkrtz(a, b);
    return cv.h;
}

// Build fragment-ordered tables: for gi = (kt*16 + wt)*64 + lane,
// lane = quad*16 + l15, n = 16*wt+l15, j0 = kt*32+quad*8:
//   Mtab[gi] = M[n][j0..j0+7] (f16), Ptab[gi] = P[n][j0..j0+7] (f16),
//   Itab[gi] = 1/(n*256 + j0 + e + 2), e=0..7 (f32, two float4)
__global__ void build_tabs(const float* __restrict__ M1, const float* __restrict__ P1,
                           const float* __restrict__ M2, const float* __restrict__ P2,
                           char* __restrict__ ws)
{
    int gid   = blockIdx.x * 256 + threadIdx.x;   // 0..16383
    int layer = gid >> 13;
    int gi    = gid & 8191;                        // idx*64 + lane
    int idx   = gi >> 6;                           // 0..127 = kt*16 + wt
    int lane  = gi & 63;
    int kt    = idx >> 4;
    int wt    = idx & 15;
    int l15   = lane & 15, quad = lane >> 4;
    int n     = 16 * wt + l15;
    int j0    = kt * 32 + quad * 8;

    const float* Msrc = layer ? M2 : M1;
    const float* Psrc = layer ? P2 : P1;

    union { half8 h; half2t h2[4]; } mh, ph;
    float iv[8];
    #pragma unroll
    for (int e = 0; e < 4; ++e) {
        float ma = Msrc[(size_t)n * DD + j0 + 2 * e];
        float mb = Msrc[(size_t)n * DD + j0 + 2 * e + 1];
        float pa = Psrc[(size_t)n * DD + j0 + 2 * e];
        float pb = Psrc[(size_t)n * DD + j0 + 2 * e + 1];
        mh.h2[e] = pkrtz(ma, mb);
        ph.h2[e] = pkrtz(pa, pb);
        iv[2 * e]     = 1.0f / (float)(n * DD + j0 + 2 * e + 2);
        iv[2 * e + 1] = 1.0f / (float)(n * DD + j0 + 2 * e + 3);
    }
    char* base = ws + (size_t)layer * LAYER_BYTES;
    ((half8*)base)[gi]                       = mh.h;
    ((half8*)(base + PTAB_OFF))[gi]          = ph.h;
    float4* it = (float4*)(base + ITAB_OFF);
    it[2 * gi]     = make_float4(iv[0], iv[1], iv[2], iv[3]);
    it[2 * gi + 1] = make_float4(iv[4], iv[5], iv[6], iv[7]);
}

// Block = 1024 threads (16 waves), s-pair (s0, s0+1) per block. Grid 512.
// __launch_bounds__(1024, 8) -> 2 blocks/CU = 32 waves/CU (2x the old 16).
// Wave w owns n-tile w (cols 16w..16w+15). A rows m = sl*8+b. Residual in regs.
// Phase loops software-pipeline the next iteration's table/LDS loads (distance 1)
// so each ~250-cycle cos/VALU block covers the next L2 load latency.
template<bool TABS>
__global__ __launch_bounds__(1024, 8)
void fused_hierddpm(const float* __restrict__ seq,
                    const float* __restrict__ M1, const float* __restrict__ P1,
                    const float* __restrict__ g1, const float* __restrict__ be1,
                    const float* __restrict__ M2, const float* __restrict__ P2,
                    const float* __restrict__ g2, const float* __restrict__ be2,
                    const char* __restrict__ ws,
                    float* __restrict__ out)
{
    __shared__ __align__(16) _Float16 xsb[16][XSTRIDE]; // input / layer-out, f16, A-layout
    __shared__ __align__(16) _Float16 xtb[16][XSTRIDE]; // LN'd xt, f16
    __shared__ float2 stats[16][16];                    // [wave][row] partial (sum, sumsq)

    const int tid  = threadIdx.x;
    const int w    = tid >> 6;       // wave 0..15, owns n-tile w
    const int lane = tid & 63;
    const int l15  = lane & 15;
    const int quad = lane >> 4;
    const int s0   = blockIdx.x * 2;
    const float k0 = (float)s0, k1 = (float)(s0 + 1);
    const int col  = 16 * w + l15;   // this wave's output column

    // ---- stage x into xsb (f16, rows m = sl*8+b), coalesced float4 reads
    {
        const float4* seq4 = (const float4*)seq;
        int sl = tid >> 9;
        int rm = tid & 511;
        int b  = rm >> 6, j4 = rm & 63;
        float4 x = seq4[((size_t)b * SS + s0 + sl) * 64 + j4];
        half2t* dst = (half2t*)&xsb[sl * 8 + b][4 * j4];
        dst[0] = pkrtz(x.x, x.y);
        dst[1] = pkrtz(x.z, x.w);
    }

    // ---- residual in registers: row m = quad*4+reg -> (b = m&7, sl = m>>3)
    float res[4];
    #pragma unroll
    for (int reg = 0; reg < 4; ++reg) {
        int m = quad * 4 + reg;
        res[reg] = seq[((size_t)(m & 7) * SS + s0 + (m >> 3)) * DD + col];
    }
    __syncthreads();

    #pragma unroll 1
    for (int layer = 0; layer < 2; ++layer) {
        const float* M  = layer ? M2  : M1;
        const float* P  = layer ? P2  : P1;
        const float* g  = layer ? g2  : g1;
        const float* be = layer ? be2 : be1;
        const char*  lbase = ws + (size_t)layer * LAYER_BYTES;
        const half8*  Mtab = (const half8*)lbase;
        const half8*  Ptab = (const half8*)(lbase + PTAB_OFF);
        const float4* Itab = (const float4*)(lbase + ITAB_OFF);

        // ======== phase A: xt = x @ M^T (f16 MFMA); wave owns n-tile w
        float4v acc1 = (float4v){0.f, 0.f, 0.f, 0.f};

        if (TABS) {
            half8 aN = *(const half8*)&xsb[l15][quad * 8];
            half8 bN = Mtab[w * 64 + lane];
            #pragma unroll 1
            for (int kt = 0; kt < 8; ++kt) {
                half8 aC = aN, bC = bN;
                if (kt < 7) {
                    aN = *(const half8*)&xsb[l15][(kt + 1) * 32 + quad * 8];
                    bN = Mtab[((kt + 1) * 16 + w) * 64 + lane];
                }
                acc1 = __builtin_amdgcn_mfma_f32_16x16x32_f16(aC, bC, acc1, 0, 0, 0);
            }
        } else {
            #pragma unroll 1
            for (int kt = 0; kt < 8; ++kt) {
                half8 a = *(const half8*)&xsb[l15][kt * 32 + quad * 8];
                int n = 16 * w + l15;
                const float4* Mr = (const float4*)M + ((size_t)n * 64 + kt * 8 + quad * 2);
                float4 m0 = Mr[0], m1 = Mr[1];
                union { half8 h; half2t h2[4]; } bb2;
                bb2.h2[0] = pkrtz(m0.x, m0.y);
                bb2.h2[1] = pkrtz(m0.z, m0.w);
                bb2.h2[2] = pkrtz(m1.x, m1.y);
                bb2.h2[3] = pkrtz(m1.z, m1.w);
                acc1 = __builtin_amdgcn_mfma_f32_16x16x32_f16(a, bb2.h, acc1, 0, 0, 0);
            }
        }

        // ======== LayerNorm in C-register layout (row m = quad*4+reg)
        #pragma unroll
        for (int reg = 0; reg < 4; ++reg) {
            float sm = acc1[reg];
            float sq = acc1[reg] * acc1[reg];
            #pragma unroll
            for (int off = 1; off < 16; off <<= 1) {
                sm += __shfl_xor(sm, off, 64);
                sq += __shfl_xor(sq, off, 64);
            }
            if (l15 == 0) stats[w][quad * 4 + reg] = make_float2(sm, sq);
        }
        __syncthreads();
        {
            float gv = g[col], bv = be[col];
            #pragma unroll
            for (int reg = 0; reg < 4; ++reg) {
                int m = quad * 4 + reg;
                float sm = 0.f, sq = 0.f;
                #pragma unroll
                for (int ww = 0; ww < 16; ++ww) {
                    float2 v = stats[ww][m];
                    sm += v.x; sq += v.y;
                }
                float mm = sm * (1.f / DD);
                float rs = rsqrtf(sq * (1.f / DD) - mm * mm + 1e-5f);
                xtb[m][col] = (_Float16)fmaf((acc1[reg] - mm) * rs, gv, bv);
            }
        }
        __syncthreads();   // xtb ready for phase B

        // ======== phase B: Nk = xt @ W_s^T; W = P * cos generated in regs (f16)
        float4v accS0 = (float4v){0.f, 0.f, 0.f, 0.f};
        float4v accS1 = (float4v){0.f, 0.f, 0.f, 0.f};

        if (TABS) {
            int gi0 = w * 64 + lane;
            half8 aN = *(const half8*)&xtb[l15][quad * 8];
            half8 pN = Ptab[gi0];
            float4 iN0 = Itab[2 * gi0], iN1 = Itab[2 * gi0 + 1];
            #pragma unroll 1
            for (int kt = 0; kt < 8; ++kt) {
                half8 aC = aN;
                union { half8 h; half2t h2[4]; } pv; pv.h = pN;
                float iv[8] = {iN0.x, iN0.y, iN0.z, iN0.w, iN1.x, iN1.y, iN1.z, iN1.w};
                if (kt < 7) {   // prefetch next iteration (covers L2 latency with cos block)
                    int gin = ((kt + 1) * 16 + w) * 64 + lane;
                    aN  = *(const half8*)&xtb[l15][(kt + 1) * 32 + quad * 8];
                    pN  = Ptab[gin];
                    iN0 = Itab[2 * gin];
                    iN1 = Itab[2 * gin + 1];
                }
                union { half8 h; half2t h2[4]; } b0, b1;
                #pragma unroll
                for (int e = 0; e < 4; ++e) {
                    float ia = iv[2 * e], ib = iv[2 * e + 1];
                    half2t c0 = pkrtz(
                        __builtin_amdgcn_cosf(__builtin_amdgcn_fractf(k0 * ia)),
                        __builtin_amdgcn_cosf(__builtin_amdgcn_fractf(k0 * ib)));
                    half2t c1 = pkrtz(
                        __builtin_amdgcn_cosf(__builtin_amdgcn_fractf(k1 * ia)),
                        __builtin_amdgcn_cosf(__builtin_amdgcn_fractf(k1 * ib)));
                    b0.h2[e] = pv.h2[e] * c0;   // v_pk_mul_f16
                    b1.h2[e] = pv.h2[e] * c1;
                }
                accS0 = __builtin_amdgcn_mfma_f32_16x16x32_f16(aC, b0.h, accS0, 0, 0, 0);
                accS1 = __builtin_amdgcn_mfma_f32_16x16x32_f16(aC, b1.h, accS1, 0, 0, 0);
            }
        } else {
            #pragma unroll 1
            for (int kt = 0; kt < 8; ++kt) {
                half8 a = *(const half8*)&xtb[l15][kt * 32 + quad * 8];
                int n = 16 * w + l15;
                const float4* Pr = (const float4*)P + ((size_t)n * 64 + kt * 8 + quad * 2);
                float4 p0 = Pr[0], p1 = Pr[1];
                union { half8 h; half2t h2[4]; } pv;
                pv.h2[0] = pkrtz(p0.x, p0.y);
                pv.h2[1] = pkrtz(p0.z, p0.w);
                pv.h2[2] = pkrtz(p1.x, p1.y);
                pv.h2[3] = pkrtz(p1.z, p1.w);
                float pbase = (float)(n * DD + kt * 32 + quad * 8 + 2);
                union { half8 h; half2t h2[4]; } b0, b1;
                #pragma unroll
                for (int e = 0; e < 4; ++e) {
                    float ia = __builtin_amdgcn_rcpf(pbase + (float)(2 * e));
                    float ib = __builtin_amdgcn_rcpf(pbase + (float)(2 * e + 1));
                    half2t c0 = pkrtz(
                        __builtin_amdgcn_cosf(__builtin_amdgcn_fractf(k0 * ia)),
                        __builtin_amdgcn_cosf(__builtin_amdgcn_fractf(k0 * ib)));
                    half2t c1 = pkrtz(
                        __builtin_amdgcn_cosf(__builtin_amdgcn_fractf(k1 * ia)),
                        __builtin_amdgcn_cosf(__builtin_amdgcn_fractf(k1 * ib)));
                    b0.h2[e] = pv.h2[e] * c0;
                    b1.h2[e] = pv.h2[e] * c1;
                }
                accS0 = __builtin_amdgcn_mfma_f32_16x16x32_f16(a, b0.h, accS0, 0, 0, 0);
                accS1 = __builtin_amdgcn_mfma_f32_16x16x32_f16(a, b1.h, accS1, 0, 0, 0);
            }
        }

        // ======== epilogue: accS0 valid for rows 0..7 (quad<2), accS1 for 8..15
        #pragma unroll
        for (int reg = 0; reg < 4; ++reg) {
            int m = quad * 4 + reg;
            float av = ((quad < 2) ? accS0[reg] : accS1[reg]) + res[reg];
            if (layer == 0) {
                res[reg] = av;                 // next layer's residual
                xsb[m][col] = (_Float16)av;    // next layer's A-matrix
            } else {
                out[((size_t)(m & 7) * SS + s0 + (m >> 3)) * DD + col] = av;
            }
        }
        if (layer == 0) __syncthreads();
    }
}

extern "C" void kernel_launch(void* const* d_in, const int* in_sizes, int n_in,
                              void* d_out, int out_size, void* d_ws, size_t ws_size,
                              hipStream_t stream)
{
    const float* seq = (const float*)d_in[0];
    const float* M1  = (const float*)d_in[1];
    const float* P1  = (const float*)d_in[2];
    const float* g1  = (const float*)d_in[3];
    const float* b1  = (const float*)d_in[4];
    const float* M2  = (const float*)d_in[5];
    const float* P2  = (const float*)d_in[6];
    const float* g2  = (const float*)d_in[7];
    const float* b2  = (const float*)d_in[8];
    float* out = (float*)d_out;

    if (ws_size >= WS_NEEDED) {
        build_tabs<<<64, 256, 0, stream>>>(M1, P1, M2, P2, (char*)d_ws);
        fused_hierddpm<true><<<SS / 2, 1024, 0, stream>>>(
            seq, M1, P1, g1, b1, M2, P2, g2, b2, (const char*)d_ws, out);
    } else {
        fused_hierddpm<false><<<SS / 2, 1024, 0, stream>>>(
            seq, M1, P1, g1, b1, M2, P2, g2, b2, nullptr, out);
    }
}

// Round 2
// 147.598 us; speedup vs baseline: 1.2049x; 1.2049x over previous
//
#include <hip/hip_runtime.h>

#define DD 256
#define BB 8
#define SS 1024
#define XSTRIDE 264   // f16 elems per LDS row (528 B, 16B-aligned)

// ws layout per layer (bytes): Mtab 131072 | Ptab 131072 = 262144 (Itab dropped: rcp on the fly)
#define LAYER_BYTES 262144
#define PTAB_OFF    131072
#define WS_NEEDED   (2 * LAYER_BYTES)

typedef _Float16 half8  __attribute__((ext_vector_type(8)));
typedef _Float16 half2t __attribute__((ext_vector_type(2)));
typedef __fp16   fp16x2 __attribute__((ext_vector_type(2)));
typedef __attribute__((ext_vector_type(4))) float float4v;

__device__ __forceinline__ half2t pkrtz(float a, float b) {
    union { fp16x2 f; half2t h; } cv;
    cv.f = __builtin_amdgcn_cvt_pkrtz(a, b);
    return cv.h;
}

// Fragment-ordered f16 tables: for gi = (kt*16 + wt)*64 + lane,
// lane = quad*16 + l15, n = 16*wt+l15, j0 = kt*32+quad*8:
//   Mtab[gi] = M[n][j0..j0+7], Ptab[gi] = P[n][j0..j0+7]
__global__ void build_tabs(const float* __restrict__ M1, const float* __restrict__ P1,
                           const float* __restrict__ M2, const float* __restrict__ P2,
                           char* __restrict__ ws)
{
    int gid   = blockIdx.x * 256 + threadIdx.x;   // 0..16383
    int layer = gid >> 13;
    int gi    = gid & 8191;                        // idx*64 + lane
    int idx   = gi >> 6;                           // 0..127 = kt*16 + wt
    int lane  = gi & 63;
    int wt    = idx & 15;
    int l15   = lane & 15, quad = lane >> 4;
    int kt    = idx >> 4;
    int n     = 16 * wt + l15;
    int j0    = kt * 32 + quad * 8;

    const float* Msrc = layer ? M2 : M1;
    const float* Psrc = layer ? P2 : P1;

    union { half8 h; half2t h2[4]; } mh, ph;
    #pragma unroll
    for (int e = 0; e < 4; ++e) {
        float ma = Msrc[(size_t)n * DD + j0 + 2 * e];
        float mb = Msrc[(size_t)n * DD + j0 + 2 * e + 1];
        float pa = Psrc[(size_t)n * DD + j0 + 2 * e];
        float pb = Psrc[(size_t)n * DD + j0 + 2 * e + 1];
        mh.h2[e] = pkrtz(ma, mb);
        ph.h2[e] = pkrtz(pa, pb);
    }
    char* base = ws + (size_t)layer * LAYER_BYTES;
    ((half8*)base)[gi]              = mh.h;
    ((half8*)(base + PTAB_OFF))[gi] = ph.h;
}

// Block = 512 threads (8 waves). Grid 1024: block = (s-pair sp, batch-half bh).
// Rows r = sl*4 + bl (8 valid rows: b = bh*4+bl, s = s0+sl); MFMA rows 8-15 unused
// (garbage contained: only discarded C rows; quads 2-3 zero xtb rows 8-15).
// Wave w owns n-tiles 2w, 2w+1. Residual in registers (quads 0-1).
// 4 blocks/CU = 32 waves/CU (2x round-0's grid-limited 16) at <=64 total regs,
// 3 blocks/CU if regalloc lands 65-85 -- launch_bounds(512,6) avoids forced spill.
template<bool TABS>
__global__ __launch_bounds__(512, 6)
void fused_hierddpm(const float* __restrict__ seq,
                    const float* __restrict__ M1, const float* __restrict__ P1,
                    const float* __restrict__ g1, const float* __restrict__ be1,
                    const float* __restrict__ M2, const float* __restrict__ P2,
                    const float* __restrict__ g2, const float* __restrict__ be2,
                    const char* __restrict__ ws,
                    float* __restrict__ out)
{
    __shared__ __align__(16) _Float16 xsb[16][XSTRIDE]; // input / layer-out, f16, A-layout
    __shared__ __align__(16) _Float16 xtb[16][XSTRIDE]; // LN'd xt, f16
    __shared__ __align__(16) float2 stats[8][8];        // [row][wave] partial (sum, sumsq)

    const int tid  = threadIdx.x;
    const int w    = tid >> 6;
    const int lane = tid & 63;
    const int l15  = lane & 15;
    const int quad = lane >> 4;
    const int sp   = blockIdx.x >> 1;
    const int bh   = blockIdx.x & 1;     // batch half: rows b = bh*4 .. bh*4+3
    const int s0   = sp * 2;
    const float k0 = (float)s0, k1 = (float)(s0 + 1);

    // ---- stage x rows r = sl*4+bl into xsb (f16), coalesced float4 reads
    {
        const float4* seq4 = (const float4*)seq;
        int r  = tid >> 6;                 // 0..7
        int j4 = tid & 63;
        int b  = bh * 4 + (r & 3);
        int sl = r >> 2;
        float4 x = seq4[((size_t)b * SS + s0 + sl) * 64 + j4];
        half2t* dst = (half2t*)&xsb[r][4 * j4];
        dst[0] = pkrtz(x.x, x.y);
        dst[1] = pkrtz(x.z, x.w);
    }

    // ---- residual in registers (quads 0-1 only): row m = quad*4+reg -> sl=quad, bl=reg
    float res[2][4] = {};
    if (quad < 2) {
        #pragma unroll
        for (int t = 0; t < 2; ++t) {
            int col = 16 * (2 * w + t) + l15;
            #pragma unroll
            for (int reg = 0; reg < 4; ++reg)
                res[t][reg] = seq[((size_t)(bh * 4 + reg) * SS + s0 + quad) * DD + col];
        }
    }
    __syncthreads();

    #pragma unroll 1
    for (int layer = 0; layer < 2; ++layer) {
        const float* M  = layer ? M2  : M1;
        const float* P  = layer ? P2  : P1;
        const float* g  = layer ? g2  : g1;
        const float* be = layer ? be2 : be1;
        const char*  lbase = ws + (size_t)layer * LAYER_BYTES;
        const half8* Mtab = (const half8*)lbase;
        const half8* Ptab = (const half8*)(lbase + PTAB_OFF);

        // ======== phase A: xt = x @ M^T (f16 MFMA); wave owns n-tiles 2w,2w+1
        float4v acc1[2];
        acc1[0] = (float4v){0.f, 0.f, 0.f, 0.f};
        acc1[1] = (float4v){0.f, 0.f, 0.f, 0.f};

        #pragma unroll 2
        for (int kt = 0; kt < 8; ++kt) {
            half8 a = *(const half8*)&xsb[l15][kt * 32 + quad * 8];
            #pragma unroll
            for (int t = 0; t < 2; ++t) {
                half8 bfrag;
                if (TABS) {
                    bfrag = Mtab[(kt * 16 + 2 * w + t) * 64 + lane];
                } else {
                    int n = 16 * (2 * w + t) + l15;
                    const float4* Mr = (const float4*)M +
                        ((size_t)n * 64 + kt * 8 + quad * 2);
                    float4 m0 = Mr[0], m1 = Mr[1];
                    union { half8 h; half2t h2[4]; } bb2;
                    bb2.h2[0] = pkrtz(m0.x, m0.y);
                    bb2.h2[1] = pkrtz(m0.z, m0.w);
                    bb2.h2[2] = pkrtz(m1.x, m1.y);
                    bb2.h2[3] = pkrtz(m1.z, m1.w);
                    bfrag = bb2.h;
                }
                acc1[t] = __builtin_amdgcn_mfma_f32_16x16x32_f16(a, bfrag, acc1[t], 0, 0, 0);
            }
        }

        // ======== LayerNorm (rows 0-7 valid; quads 2-3 contained garbage)
        #pragma unroll
        for (int reg = 0; reg < 4; ++reg) {
            float v0 = acc1[0][reg], v1 = acc1[1][reg];
            float sm = v0 + v1;
            float sq = fmaf(v0, v0, v1 * v1);
            #pragma unroll
            for (int off = 1; off < 16; off <<= 1) {
                sm += __shfl_xor(sm, off, 64);
                sq += __shfl_xor(sq, off, 64);
            }
            if (l15 == 0 && quad < 2) stats[quad * 4 + reg][w] = make_float2(sm, sq);
        }
        __syncthreads();
        if (quad < 2) {
            float gv[2], bv[2];
            #pragma unroll
            for (int t = 0; t < 2; ++t) {
                int col = 16 * (2 * w + t) + l15;
                gv[t] = g[col]; bv[t] = be[col];
            }
            #pragma unroll
            for (int reg = 0; reg < 4; ++reg) {
                int m = quad * 4 + reg;
                const float4* sp4 = (const float4*)&stats[m][0];
                float4 q0 = sp4[0], q1 = sp4[1], q2 = sp4[2], q3 = sp4[3];
                float sm = (q0.x + q0.z) + (q1.x + q1.z) + (q2.x + q2.z) + (q3.x + q3.z);
                float sq = (q0.y + q0.w) + (q1.y + q1.w) + (q2.y + q2.w) + (q3.y + q3.w);
                float mm = sm * (1.f / DD);
                float rs = rsqrtf(sq * (1.f / DD) - mm * mm + 1e-5f);
                #pragma unroll
                for (int t = 0; t < 2; ++t) {
                    int col = 16 * (2 * w + t) + l15;
                    xtb[m][col] = (_Float16)fmaf((acc1[t][reg] - mm) * rs, gv[t], bv[t]);
                }
            }
        } else {
            #pragma unroll
            for (int reg = 0; reg < 4; ++reg)
                #pragma unroll
                for (int t = 0; t < 2; ++t)
                    xtb[quad * 4 + reg][16 * (2 * w + t) + l15] = (_Float16)0.f;
        }
        __syncthreads();   // xtb ready for phase B

        // ======== phase B: Nk = xt @ W_s^T; W = P * cos, 1/period via v_rcp
        float4v accS[2][2];   // [k][t], static indices only
        #pragma unroll
        for (int k = 0; k < 2; ++k)
            #pragma unroll
            for (int t = 0; t < 2; ++t) accS[k][t] = (float4v){0.f, 0.f, 0.f, 0.f};

        #pragma unroll 2
        for (int kt = 0; kt < 8; ++kt) {
            half8 a = *(const half8*)&xtb[l15][kt * 32 + quad * 8];
            #pragma unroll
            for (int t = 0; t < 2; ++t) {
                int n = 16 * (2 * w + t) + l15;
                union { half8 h; half2t h2[4]; } pv;
                if (TABS) {
                    pv.h = Ptab[(kt * 16 + 2 * w + t) * 64 + lane];
                } else {
                    const float4* Pr = (const float4*)P +
                        ((size_t)n * 64 + kt * 8 + quad * 2);
                    float4 p0 = Pr[0], p1 = Pr[1];
                    pv.h2[0] = pkrtz(p0.x, p0.y);
                    pv.h2[1] = pkrtz(p0.z, p0.w);
                    pv.h2[2] = pkrtz(p1.x, p1.y);
                    pv.h2[3] = pkrtz(p1.z, p1.w);
                }
                float pbase = (float)(n * DD + kt * 32 + quad * 8 + 2);
                union { half8 h; half2t h2[4]; } b0, b1;
                #pragma unroll
                for (int e = 0; e < 4; ++e) {
                    float ia = __builtin_amdgcn_rcpf(pbase + (float)(2 * e));
                    float ib = __builtin_amdgcn_rcpf(pbase + (float)(2 * e + 1));
                    half2t c0 = pkrtz(
                        __builtin_amdgcn_cosf(__builtin_amdgcn_fractf(k0 * ia)),
                        __builtin_amdgcn_cosf(__builtin_amdgcn_fractf(k0 * ib)));
                    half2t c1 = pkrtz(
                        __builtin_amdgcn_cosf(__builtin_amdgcn_fractf(k1 * ia)),
                        __builtin_amdgcn_cosf(__builtin_amdgcn_fractf(k1 * ib)));
                    b0.h2[e] = pv.h2[e] * c0;   // v_pk_mul_f16
                    b1.h2[e] = pv.h2[e] * c1;
                }
                accS[0][t] = __builtin_amdgcn_mfma_f32_16x16x32_f16(a, b0.h, accS[0][t], 0, 0, 0);
                accS[1][t] = __builtin_amdgcn_mfma_f32_16x16x32_f16(a, b1.h, accS[1][t], 0, 0, 0);
            }
        }

        // ======== epilogue: quad 0 -> k0 rows 0-3, quad 1 -> k1 rows 4-7
        if (quad < 2) {
            #pragma unroll
            for (int t = 0; t < 2; ++t) {
                int col = 16 * (2 * w + t) + l15;
                float4v av = (quad == 0) ? accS[0][t] : accS[1][t];  // static idx
                #pragma unroll
                for (int reg = 0; reg < 4; ++reg) {
                    int m = quad * 4 + reg;
                    float val = av[reg] + res[t][reg];
                    if (layer == 0) {
                        res[t][reg] = val;             // next layer's residual
                        xsb[m][col] = (_Float16)val;   // next layer's A-matrix
                    } else {
                        out[((size_t)(bh * 4 + reg) * SS + s0 + quad) * DD + col] = val;
                    }
                }
            }
        }
        if (layer == 0) __syncthreads();
    }
}

extern "C" void kernel_launch(void* const* d_in, const int* in_sizes, int n_in,
                              void* d_out, int out_size, void* d_ws, size_t ws_size,
                              hipStream_t stream)
{
    const float* seq = (const float*)d_in[0];
    const float* M1  = (const float*)d_in[1];
    const float* P1  = (const float*)d_in[2];
    const float* g1  = (const float*)d_in[3];
    const float* b1  = (const float*)d_in[4];
    const float* M2  = (const float*)d_in[5];
    const float* P2  = (const float*)d_in[6];
    const float* g2  = (const float*)d_in[7];
    const float* b2  = (const float*)d_in[8];
    float* out = (float*)d_out;

    if (ws_size >= WS_NEEDED) {
        build_tabs<<<64, 256, 0, stream>>>(M1, P1, M2, P2, (char*)d_ws);
        fused_hierddpm<true><<<SS, 512, 0, stream>>>(
            seq, M1, P1, g1, b1, M2, P2, g2, b2, (const char*)d_ws, out);
    } else {
        fused_hierddpm<false><<<SS, 512, 0, stream>>>(
            seq, M1, P1, g1, b1, M2, P2, g2, b2, nullptr, out);
    }
}

// Round 4
// 117.240 us; speedup vs baseline: 1.5168x; 1.2589x over previous
//
#include <hip/hip_runtime.h>

#define DD 256
#define BB 8
#define SS 1024
#define XSTRIDE 264   // f16 elems per LDS row (528 B, 16B-aligned)
#define RSTRIDE 260   // f32 elems per residual LDS row (1040 B, 16B-aligned)

// ws layout per layer (bytes): Mtab 131072 | Ptab 131072 (Itab dropped: rcp on the fly)
#define LAYER_BYTES 262144
#define PTAB_OFF    131072
#define WS_NEEDED   (2 * LAYER_BYTES)

typedef _Float16 half8  __attribute__((ext_vector_type(8)));
typedef _Float16 half2t __attribute__((ext_vector_type(2)));
typedef __fp16   fp16x2 __attribute__((ext_vector_type(2)));
typedef __attribute__((ext_vector_type(4))) float float4v;

union h8u { half8 h; half2t h2[4]; };   // named: assignable across uses

__device__ __forceinline__ half2t pkrtz(float a, float b) {
    union { fp16x2 f; half2t h; } cv;
    cv.f = __builtin_amdgcn_cvt_pkrtz(a, b);
    return cv.h;
}

__device__ __forceinline__ float cosrev(float x) {   // cos(2*pi*x)
    return __builtin_amdgcn_cosf(__builtin_amdgcn_fractf(x));
}

// Fragment-ordered f16 tables: for gi = (kt*16 + wt)*64 + lane,
// lane = quad*16 + l15, n = 16*wt+l15, j0 = kt*32+quad*8:
//   Mtab[gi] = M[n][j0..j0+7], Ptab[gi] = P[n][j0..j0+7]
__global__ void build_tabs(const float* __restrict__ M1, const float* __restrict__ P1,
                           const float* __restrict__ M2, const float* __restrict__ P2,
                           char* __restrict__ ws)
{
    int gid   = blockIdx.x * 256 + threadIdx.x;   // 0..16383
    int layer = gid >> 13;
    int gi    = gid & 8191;                        // idx*64 + lane
    int idx   = gi >> 6;                           // 0..127 = kt*16 + wt
    int lane  = gi & 63;
    int wt    = idx & 15;
    int l15   = lane & 15, quad = lane >> 4;
    int kt    = idx >> 4;
    int n     = 16 * wt + l15;
    int j0    = kt * 32 + quad * 8;

    const float* Msrc = layer ? M2 : M1;
    const float* Psrc = layer ? P2 : P1;

    h8u mh, ph;
    #pragma unroll
    for (int e = 0; e < 4; ++e) {
        float ma = Msrc[(size_t)n * DD + j0 + 2 * e];
        float mb = Msrc[(size_t)n * DD + j0 + 2 * e + 1];
        float pa = Psrc[(size_t)n * DD + j0 + 2 * e];
        float pb = Psrc[(size_t)n * DD + j0 + 2 * e + 1];
        mh.h2[e] = pkrtz(ma, mb);
        ph.h2[e] = pkrtz(pa, pb);
    }
    char* base = ws + (size_t)layer * LAYER_BYTES;
    ((half8*)base)[gi]              = mh.h;
    ((half8*)(base + PTAB_OFF))[gi] = ph.h;
}

// Block = 512 threads (8 waves), s-pair (s0, s0+1) per block, grid 512 (work-optimal
// split: each cos and each 1/p computed exactly once chip-wide; 2 s share one rcp).
// Wave w owns n-tiles 2w, 2w+1. A/C rows r = sl*8+b. Residual in LDS (f32).
// Both MFMA phases run an explicit distance-1 software pipeline: next iteration's
// Mtab/Ptab (L2, ~250cy) and A-fragment (LDS) loads issue before the current
// iteration's ~290-cycle cos/VALU block, so table latency is covered in-wave
// (grid=512 caps us at 2 blocks/CU = 4 waves/SIMD; TLP alone left 55% idle).
template<bool TABS>
__global__ __launch_bounds__(512, 4)
void fused_hierddpm(const float* __restrict__ seq,
                    const float* __restrict__ M1, const float* __restrict__ P1,
                    const float* __restrict__ g1, const float* __restrict__ be1,
                    const float* __restrict__ M2, const float* __restrict__ P2,
                    const float* __restrict__ g2, const float* __restrict__ be2,
                    const char* __restrict__ ws,
                    float* __restrict__ out)
{
    __shared__ __align__(16) _Float16 xsb[16][XSTRIDE];  // input / layer-out, f16, A-layout
    __shared__ __align__(16) _Float16 xtb[16][XSTRIDE];  // LN'd xt, f16
    __shared__ __align__(16) float2 stats[16][8];        // [row][wave] partial (sum, sumsq)
    __shared__ __align__(16) float res_lds[16][RSTRIDE]; // f32 residual (frees 8 live VGPRs)

    const int tid  = threadIdx.x;
    const int w    = tid >> 6;
    const int lane = tid & 63;
    const int l15  = lane & 15;
    const int quad = lane >> 4;
    const int s0   = blockIdx.x * 2;
    const float k0 = (float)s0;

    // ---- stage x into xsb (f16) and res_lds (f32), one coalesced float4 pass
    {
        const float4* seq4 = (const float4*)seq;
        #pragma unroll
        for (int u = 0; u < 2; ++u) {
            int v  = tid + 512 * u;          // float4 index 0..1023
            int sl = v >> 9;
            int rm = v & 511;
            int b  = rm >> 6, j4 = rm & 63;
            float4 x = seq4[((size_t)b * SS + s0 + sl) * 64 + j4];
            int r = sl * 8 + b;
            half2t* dst = (half2t*)&xsb[r][4 * j4];
            dst[0] = pkrtz(x.x, x.y);
            dst[1] = pkrtz(x.z, x.w);
            *(float4*)&res_lds[r][4 * j4] = x;
        }
    }
    __syncthreads();

    #pragma unroll 1
    for (int layer = 0; layer < 2; ++layer) {
        const float* M  = layer ? M2  : M1;
        const float* P  = layer ? P2  : P1;
        const float* g  = layer ? g2  : g1;
        const float* be = layer ? be2 : be1;
        const char*  lbase = ws + (size_t)layer * LAYER_BYTES;
        const half8* Mtab = (const half8*)lbase;
        const half8* Ptab = (const half8*)(lbase + PTAB_OFF);

        // ======== phase A: xt = x @ M^T, distance-1 pipelined
        float4v acc1[2];
        acc1[0] = (float4v){0.f, 0.f, 0.f, 0.f};
        acc1[1] = (float4v){0.f, 0.f, 0.f, 0.f};

        half8 aN = *(const half8*)&xsb[l15][quad * 8];
        half8 b0N, b1N;
        if (TABS) {
            b0N = Mtab[(2 * w) * 64 + lane];
            b1N = Mtab[(2 * w + 1) * 64 + lane];
        }
        #pragma unroll 1
        for (int kt = 0; kt < 8; ++kt) {
            half8 aC = aN;
            half8 b0C, b1C;
            if (TABS) {
                b0C = b0N; b1C = b1N;
            } else {
                #pragma unroll
                for (int t = 0; t < 2; ++t) {
                    int n = 16 * (2 * w + t) + l15;
                    const float4* Mr = (const float4*)M + ((size_t)n * 64 + kt * 8 + quad * 2);
                    float4 m0 = Mr[0], m1 = Mr[1];
                    h8u bb2;
                    bb2.h2[0] = pkrtz(m0.x, m0.y);
                    bb2.h2[1] = pkrtz(m0.z, m0.w);
                    bb2.h2[2] = pkrtz(m1.x, m1.y);
                    bb2.h2[3] = pkrtz(m1.z, m1.w);
                    if (t == 0) b0C = bb2.h; else b1C = bb2.h;
                }
            }
            if (kt < 7) {
                aN = *(const half8*)&xsb[l15][(kt + 1) * 32 + quad * 8];
                if (TABS) {
                    b0N = Mtab[((kt + 1) * 16 + 2 * w) * 64 + lane];
                    b1N = Mtab[((kt + 1) * 16 + 2 * w + 1) * 64 + lane];
                }
            }
            acc1[0] = __builtin_amdgcn_mfma_f32_16x16x32_f16(aC, b0C, acc1[0], 0, 0, 0);
            acc1[1] = __builtin_amdgcn_mfma_f32_16x16x32_f16(aC, b1C, acc1[1], 0, 0, 0);
        }

        // issue phase-B's first Ptab loads NOW: LayerNorm below covers their latency
        half8 p0N, p1N;
        if (TABS) {
            p0N = Ptab[(2 * w) * 64 + lane];
            p1N = Ptab[(2 * w + 1) * 64 + lane];
        }

        // ======== LayerNorm in C-register layout (row m = quad*4+reg)
        #pragma unroll
        for (int reg = 0; reg < 4; ++reg) {
            float v0 = acc1[0][reg], v1 = acc1[1][reg];
            float sm = v0 + v1;
            float sq = fmaf(v0, v0, v1 * v1);
            #pragma unroll
            for (int off = 1; off < 16; off <<= 1) {
                sm += __shfl_xor(sm, off, 64);
                sq += __shfl_xor(sq, off, 64);
            }
            if (l15 == 0) stats[quad * 4 + reg][w] = make_float2(sm, sq);
        }
        __syncthreads();
        {
            int c0i = 16 * (2 * w) + l15, c1i = 16 * (2 * w + 1) + l15;
            float gv0 = g[c0i], bv0 = be[c0i];
            float gv1 = g[c1i], bv1 = be[c1i];
            #pragma unroll
            for (int reg = 0; reg < 4; ++reg) {
                int m = quad * 4 + reg;
                const float4* s4 = (const float4*)&stats[m][0];
                float4 q0 = s4[0], q1 = s4[1], q2 = s4[2], q3 = s4[3];
                float sm = (q0.x + q0.z) + (q1.x + q1.z) + (q2.x + q2.z) + (q3.x + q3.z);
                float sq = (q0.y + q0.w) + (q1.y + q1.w) + (q2.y + q2.w) + (q3.y + q3.w);
                float mm = sm * (1.f / DD);
                float rs = rsqrtf(sq * (1.f / DD) - mm * mm + 1e-5f);
                xtb[m][c0i] = (_Float16)fmaf((acc1[0][reg] - mm) * rs, gv0, bv0);
                xtb[m][c1i] = (_Float16)fmaf((acc1[1][reg] - mm) * rs, gv1, bv1);
            }
        }
        __syncthreads();   // xtb ready for phase B

        // ======== phase B: Nk = xt @ W_s^T; W = P * cos, 1/p via v_rcp (shared k0/k1)
        float4v accS[2][2];   // [s-half][t]
        #pragma unroll
        for (int k = 0; k < 2; ++k)
            #pragma unroll
            for (int t = 0; t < 2; ++t) accS[k][t] = (float4v){0.f, 0.f, 0.f, 0.f};

        // running period base (exact integer arithmetic in f32: values < 2^17)
        float fb0 = (float)((16 * (2 * w) + l15) * DD + quad * 8 + 2);
        float fb1 = fb0 + 16.0f * DD;   // t=1 tile: n += 16
        half8 aBN = *(const half8*)&xtb[l15][quad * 8];

        #pragma unroll 1
        for (int kt = 0; kt < 8; ++kt) {
            half8 aC = aBN;
            h8u p0C, p1C;
            if (TABS) {
                p0C.h = p0N; p1C.h = p1N;
            } else {
                #pragma unroll
                for (int t = 0; t < 2; ++t) {
                    int n = 16 * (2 * w + t) + l15;
                    const float4* Pr = (const float4*)P + ((size_t)n * 64 + kt * 8 + quad * 2);
                    float4 p0 = Pr[0], p1 = Pr[1];
                    h8u pv;
                    pv.h2[0] = pkrtz(p0.x, p0.y);
                    pv.h2[1] = pkrtz(p0.z, p0.w);
                    pv.h2[2] = pkrtz(p1.x, p1.y);
                    pv.h2[3] = pkrtz(p1.z, p1.w);
                    if (t == 0) p0C = pv; else p1C = pv;
                }
            }
            if (kt < 7) {
                aBN = *(const half8*)&xtb[l15][(kt + 1) * 32 + quad * 8];
                if (TABS) {
                    p0N = Ptab[((kt + 1) * 16 + 2 * w) * 64 + lane];
                    p1N = Ptab[((kt + 1) * 16 + 2 * w + 1) * 64 + lane];
                }
            }
            // ---- t = 0
            {
                h8u bA, bB;
                #pragma unroll
                for (int e = 0; e < 4; ++e) {
                    float ia = __builtin_amdgcn_rcpf(fb0 + (float)(2 * e));
                    float ib = __builtin_amdgcn_rcpf(fb0 + (float)(2 * e + 1));
                    float a0 = k0 * ia, b0f = k0 * ib;
                    float a1 = a0 + ia, b1f = b0f + ib;   // (k0+1)/p
                    half2t c0 = pkrtz(cosrev(a0), cosrev(b0f));
                    half2t c1 = pkrtz(cosrev(a1), cosrev(b1f));
                    bA.h2[e] = p0C.h2[e] * c0;   // v_pk_mul_f16
                    bB.h2[e] = p0C.h2[e] * c1;
                }
                accS[0][0] = __builtin_amdgcn_mfma_f32_16x16x32_f16(aC, bA.h, accS[0][0], 0, 0, 0);
                accS[1][0] = __builtin_amdgcn_mfma_f32_16x16x32_f16(aC, bB.h, accS[1][0], 0, 0, 0);
                fb0 += 32.0f;
            }
            // ---- t = 1
            {
                h8u bA, bB;
                #pragma unroll
                for (int e = 0; e < 4; ++e) {
                    float ia = __builtin_amdgcn_rcpf(fb1 + (float)(2 * e));
                    float ib = __builtin_amdgcn_rcpf(fb1 + (float)(2 * e + 1));
                    float a0 = k0 * ia, b0f = k0 * ib;
                    float a1 = a0 + ia, b1f = b0f + ib;
                    half2t c0 = pkrtz(cosrev(a0), cosrev(b0f));
                    half2t c1 = pkrtz(cosrev(a1), cosrev(b1f));
                    bA.h2[e] = p1C.h2[e] * c0;
                    bB.h2[e] = p1C.h2[e] * c1;
                }
                accS[0][1] = __builtin_amdgcn_mfma_f32_16x16x32_f16(aC, bA.h, accS[0][1], 0, 0, 0);
                accS[1][1] = __builtin_amdgcn_mfma_f32_16x16x32_f16(aC, bB.h, accS[1][1], 0, 0, 0);
                fb1 += 32.0f;
            }
        }

        // ======== epilogue: rows 0-7 (quads 0-1) = s0, rows 8-15 (quads 2-3) = s1
        #pragma unroll
        for (int t = 0; t < 2; ++t) {
            int col = 16 * (2 * w + t) + l15;
            float4v av = (quad < 2) ? accS[0][t] : accS[1][t];
            int sl = quad >> 1;
            #pragma unroll
            for (int reg = 0; reg < 4; ++reg) {
                int m = quad * 4 + reg;
                int b = m & 7;
                float val = av[reg] + res_lds[m][col];
                if (layer == 0) {
                    res_lds[m][col] = val;         // next layer's residual
                    xsb[m][col] = (_Float16)val;   // next layer's A-matrix
                } else {
                    out[((size_t)b * SS + s0 + sl) * DD + col] = val;
                }
            }
        }
        if (layer == 0) __syncthreads();
    }
}

extern "C" void kernel_launch(void* const* d_in, const int* in_sizes, int n_in,
                              void* d_out, int out_size, void* d_ws, size_t ws_size,
                              hipStream_t stream)
{
    const float* seq = (const float*)d_in[0];
    const float* M1  = (const float*)d_in[1];
    const float* P1  = (const float*)d_in[2];
    const float* g1  = (const float*)d_in[3];
    const float* b1  = (const float*)d_in[4];
    const float* M2  = (const float*)d_in[5];
    const float* P2  = (const float*)d_in[6];
    const float* g2  = (const float*)d_in[7];
    const float* b2  = (const float*)d_in[8];
    float* out = (float*)d_out;

    if (ws_size >= WS_NEEDED) {
        build_tabs<<<64, 256, 0, stream>>>(M1, P1, M2, P2, (char*)d_ws);
        fused_hierddpm<true><<<SS / 2, 512, 0, stream>>>(
            seq, M1, P1, g1, b1, M2, P2, g2, b2, (const char*)d_ws, out);
    } else {
        fused_hierddpm<false><<<SS / 2, 512, 0, stream>>>(
            seq, M1, P1, g1, b1, M2, P2, g2, b2, nullptr, out);
    }
}